// Round 7
// baseline (3103.282 us; speedup 1.0000x reference)
//
#include <hip/hip_runtime.h>
#include <hip/hip_bf16.h>
#include <cstdint>
#include <cstddef>

// LSTM encoder: T=256, B=64, VOCAB=32000, E=512, H=1024
#define T_STEPS 256
#define BATCH   64
#define DE      512
#define DH      1024
#define G4      4096   // 4*DH
#define NBLK    128    // recurrence blocks; each owns 8 hidden units

typedef short  bf16x8 __attribute__((ext_vector_type(8)));   // 8 bf16 = 4 VGPRs
typedef float  f32x4  __attribute__((ext_vector_type(4)));
typedef unsigned int u32x4 __attribute__((ext_vector_type(4)));
typedef unsigned long long u64;

__device__ __forceinline__ unsigned short bf_bits(__hip_bfloat16 h) {
    union { __hip_bfloat16 h; unsigned short u; } x; x.h = h; return x.u;
}
__device__ __forceinline__ float b2f(unsigned short u) {
    union { float f; unsigned v; } x; x.v = ((unsigned)u) << 16; return x.f;
}

__device__ __forceinline__ void async_copy16(const void* gsrc, void* ldst) {
    __builtin_amdgcn_global_load_lds(
        (const __attribute__((address_space(1))) unsigned int*)gsrc,
        (__attribute__((address_space(3))) unsigned int*)ldst,
        16, 0, 0);
}

// relaxed agent-scope (LLC-coherent) accessors
__device__ __forceinline__ u64 llc_load64(const u64* p) {
    return __hip_atomic_load(p, __ATOMIC_RELAXED, __HIP_MEMORY_SCOPE_AGENT);
}
__device__ __forceinline__ void llc_store64(u64* p, u64 v) {
    __hip_atomic_store(p, v, __ATOMIC_RELAXED, __HIP_MEMORY_SCOPE_AGENT);
}
__device__ __forceinline__ unsigned llc_load32(const unsigned* p) {
    return __hip_atomic_load(p, __ATOMIC_RELAXED, __HIP_MEMORY_SCOPE_AGENT);
}
__device__ __forceinline__ void llc_store32(unsigned* p, unsigned v) {
    __hip_atomic_store(p, v, __ATOMIC_RELAXED, __HIP_MEMORY_SCOPE_AGENT);
}

// ---------------- fp32 -> bf16 convert (8 elems/thread) ----------------
__global__ void k_f32_to_bf16(const float* __restrict__ src,
                              __hip_bfloat16* __restrict__ dst, int n8) {
    int i = blockIdx.x * blockDim.x + threadIdx.x;
    if (i >= n8) return;
    const float4* s = (const float4*)src + (size_t)i * 2;
    float4 a = s[0], b = s[1];
    union { unsigned short u[8]; uint4 v; } o;
    o.u[0] = bf_bits(__float2bfloat16(a.x));
    o.u[1] = bf_bits(__float2bfloat16(a.y));
    o.u[2] = bf_bits(__float2bfloat16(a.z));
    o.u[3] = bf_bits(__float2bfloat16(a.w));
    o.u[4] = bf_bits(__float2bfloat16(b.x));
    o.u[5] = bf_bits(__float2bfloat16(b.y));
    o.u[6] = bf_bits(__float2bfloat16(b.z));
    o.u[7] = bf_bits(__float2bfloat16(b.w));
    *((uint4*)dst + i) = o.v;
}

// ---------------- embedding gather + bf16 convert ----------------
__global__ void k_gather(const int* __restrict__ xs, const float* __restrict__ emb,
                         __hip_bfloat16* __restrict__ e_bf) {
    int tid = blockIdx.x * 256 + threadIdx.x;
    int r = tid >> 6, ch = tid & 63;
    int v = xs[r];
    const float4* s = (const float4*)(emb + (size_t)v * DE + ch * 8);
    float4 a = s[0], b = s[1];
    union { unsigned short u[8]; uint4 v4; } o;
    o.u[0] = bf_bits(__float2bfloat16(a.x));
    o.u[1] = bf_bits(__float2bfloat16(a.y));
    o.u[2] = bf_bits(__float2bfloat16(a.z));
    o.u[3] = bf_bits(__float2bfloat16(a.w));
    o.u[4] = bf_bits(__float2bfloat16(b.x));
    o.u[5] = bf_bits(__float2bfloat16(b.y));
    o.u[6] = bf_bits(__float2bfloat16(b.z));
    o.u[7] = bf_bits(__float2bfloat16(b.w));
    *((uint4*)(e_bf + (size_t)r * DE) + ch) = o.v4;
}

// ---------------- x_gates GEMM -> permuted bf16 layout ----------------
// xgp[t][blk][gate][unit][batch] : (((t*128+blk)*4+g)*8+u)*64 + b
__global__ void k_gemm_xg(const __hip_bfloat16* __restrict__ A,   // [16384][512]
                          const __hip_bfloat16* __restrict__ Bt,  // [4096][512]
                          const float* __restrict__ bih, const float* __restrict__ bhh,
                          __hip_bfloat16* __restrict__ xgp) {
    __shared__ __align__(16) __hip_bfloat16 sA[128 * 32];
    __shared__ __align__(16) __hip_bfloat16 sB[128 * 32];
    const int bm = blockIdx.x >> 5;    // 128 M-tiles
    const int bn = blockIdx.x & 31;    // 32 N-tiles
    const int tid = threadIdx.x;
    const int l = tid & 63, w = tid >> 6;
    const int wm = w >> 1, wn = w & 1;
    const int lrow = l & 15, lq = l >> 4;

    f32x4 acc[4][4] = {};

    for (int kb = 0; kb < 512; kb += 32) {
#pragma unroll
        for (int q = 0; q < 2; ++q) {
            int c = q * 256 + tid;
            int row = c >> 2, seg = c & 3;
            async_copy16(A + (size_t)(bm * 128 + row) * 512 + kb + seg * 8, &sA[c * 8]);
            async_copy16(Bt + (size_t)(bn * 128 + row) * 512 + kb + seg * 8, &sB[c * 8]);
        }
        __syncthreads();
        bf16x8 af[4], bq[4];
#pragma unroll
        for (int mt = 0; mt < 4; ++mt)
            af[mt] = *(const bf16x8*)&sA[(wm * 64 + mt * 16 + lrow) * 32 + lq * 8];
#pragma unroll
        for (int nt = 0; nt < 4; ++nt)
            bq[nt] = *(const bf16x8*)&sB[(wn * 64 + nt * 16 + lrow) * 32 + lq * 8];
#pragma unroll
        for (int mt = 0; mt < 4; ++mt)
#pragma unroll
            for (int nt = 0; nt < 4; ++nt)
                acc[mt][nt] = __builtin_amdgcn_mfma_f32_16x16x32_bf16(
                    af[mt], bq[nt], acc[mt][nt], 0, 0, 0);
        __syncthreads();
    }

#pragma unroll
    for (int nt = 0; nt < 4; ++nt) {
        int n = bn * 128 + wn * 64 + nt * 16 + lrow;
        int g = n >> 10, j = n & 1023, blk = j >> 3, u = j & 7;
        float bias = bih[n] + bhh[n];
#pragma unroll
        for (int mt = 0; mt < 4; ++mt) {
#pragma unroll
            for (int r = 0; r < 4; ++r) {
                int m = bm * 128 + wm * 64 + mt * 16 + lq * 4 + r;
                int t = m >> 6, b = m & 63;
                xgp[(((size_t)(t * NBLK + blk) * 4 + g) * 8 + u) * 64 + b] =
                    __float2bfloat16(acc[mt][nt][r] + bias);
            }
        }
    }
}

// ---------------- persistent LSTM recurrence ----------------
// 128 blocks x 256 thr; block owns units j0=8*bk (32 gate rows).
// Whh slice LDS-resident (64 KB); c register-resident; h exchanged through the
// LLC, triple-buffered, chunk-major layout.
//
// ROUND-7 CHANGE (everything else identical to round 6): the h broadcast no
// longer bypasses the cache hierarchy.
//   Diagnosis: every block reads the FULL h (128KB) per step; with sc0 sc1
//   loads that is 16MB/step of agent-coherent traffic hitting the LLC
//   crossbar in a synchronized burst (4GB total, ~2TB/s sustained at the
//   measured 8.1us/step). Rounds 5/6 falsified load-serialization and tail
//   cost; this redundant broadcast is the remaining big term.
//   Fix: h loads are PLAIN CACHEABLE loads -> the 16 blocks of one XCD share
//   the line through their common L2 (first toucher fetches from LLC, rest
//   hit L2) -> ~16x less LLC demand. Staleness (buffers rotate every 3
//   steps) is handled by an acquire-agent fence (s_waitcnt + buffer_inv,
//   invalidates stale L1/L2 lines) executed by every wave right after the
//   poll, BEFORE the h loads. Producer h-stores stay sc0 sc1 (data lands at
//   LLC; no dirty L2 lines to write back). Poll exit is globally
//   synchronized (everyone waits on the same last flag), so the invs
//   cluster before the bulk of the loads.
__global__ void __launch_bounds__(256, 1) k_lstm(
        const __hip_bfloat16* __restrict__ xgp,   // [256][128][4][8][64]
        const __hip_bfloat16* __restrict__ Whh,   // [4096][1024] row-major
        __hip_bfloat16* __restrict__ hbuf,        // 3 x 65536 elems, chunk-major
        float* __restrict__ out,
        unsigned* __restrict__ flags) {           // [128], zeroed per call
    __shared__ __hip_bfloat16 sW[32768];          // 64 KB: [nt2][kb32][q4][col16][8]
    __shared__ __align__(16) __hip_bfloat16 sPack[512];
    const int tid = threadIdx.x, l = tid & 63, w = tid >> 6;
    const int lrow = l & 15, lq = l >> 4;
    const int bk = blockIdx.x;

    // load Whh slice -> LDS, frag-contiguous
#pragma unroll
    for (int f = 0; f < 16; ++f) {
        int fi = f * 256 + tid;                  // frag index 0..4095
        int col = fi & 15, q = (fi >> 4) & 3, kb = (fi >> 6) & 31, nt = fi >> 11;
        int g = (nt * 16 + col) >> 3, u = col & 7;
        async_copy16(Whh + (size_t)(g * DH + bk * 8 + u) * DH + kb * 32 + q * 8,
                     &sW[fi * 8]);
    }
    // zero my slice of h buffer 0 through the LLC
    if (tid < 128)
        llc_store64((u64*)hbuf + bk * 128 + tid, 0ull);
    asm volatile("s_waitcnt vmcnt(0)" ::: "memory");
    __syncthreads();
    if (tid == 0) llc_store32(&flags[bk], 1u);
    if (tid < 128)
        while (llc_load32(&flags[tid]) < 1u) __builtin_amdgcn_s_sleep(2);
    __syncthreads();
    // acquire: invalidate stale L1/L2 before the first plain h read
    __builtin_amdgcn_fence(__ATOMIC_ACQUIRE, "agent");
    __builtin_amdgcn_sched_barrier(0);

    const int u = l & 7, halfsel = (l >> 3) & 1;
    const int b0 = w * 16 + lq * 4;
    const int aib = lq * 128 + w * 32 + lrow * 2;   // u64 index within a k-chunk
    const unsigned aib8 = (unsigned)(aib * 8);      // byte offset within a chunk
    const int jout = bk * 8 + u;
    const u64* f64 = (const u64*)flags;
    float creg[4] = {0.f, 0.f, 0.f, 0.f};

    for (int t = 0; t < T_STEPS; ++t) {
        const u64* hin  = (const u64*)hbuf + (size_t)(t % 3) * 16384;
        u64*       hout = (u64*)hbuf + (size_t)((t + 1) % 3) * 16384;
        u64*       hob  = hout + bk * 128;       // this block's 1KB h slice

        // this step's xg (read-only, plain cached loads)
        const __hip_bfloat16* xgt = xgp + (size_t)t * (NBLK * 2048) + (size_t)bk * 2048;
        ushort4 x0 = *(const ushort4*)(xgt + (halfsel * 8 + u) * 64 + b0);
        ushort4 x1 = *(const ushort4*)(xgt + ((2 + halfsel) * 8 + u) * 64 + b0);

        // Full-K h prefetch via inline-asm loads: 32 x global_load_dwordx4,
        // all in flight at once, ONE wait. PLAIN CACHEABLE (no sc bits):
        // first toucher fills the XCD's L2, the other ~15 blocks hit L2.
        bf16x8 afr[32];
#pragma unroll
        for (int p = 0; p < 32; ++p) {
            unsigned voff = aib8 + (unsigned)(p * 4096);
            asm volatile("global_load_dwordx4 %0, %1, %2"
                         : "=v"(afr[p])
                         : "v"(voff), "s"(hin));
        }
        asm volatile("s_waitcnt vmcnt(0)" ::: "memory");
        __builtin_amdgcn_sched_barrier(0);       // rule #18: keep MFMAs below

        f32x4 a00 = {}, a01 = {}, a10 = {}, a11 = {};
#pragma unroll
        for (int kb = 0; kb < 32; ++kb) {
            bf16x8 b0f = *(const bf16x8*)&sW[(kb * 4 + lq) * 128 + lrow * 8];
            bf16x8 b1f = *(const bf16x8*)&sW[16384 + (kb * 4 + lq) * 128 + lrow * 8];
            if (kb & 1) {
                a01 = __builtin_amdgcn_mfma_f32_16x16x32_bf16(afr[kb], b0f, a01, 0, 0, 0);
                a11 = __builtin_amdgcn_mfma_f32_16x16x32_bf16(afr[kb], b1f, a11, 0, 0, 0);
            } else {
                a00 = __builtin_amdgcn_mfma_f32_16x16x32_bf16(afr[kb], b0f, a00, 0, 0, 0);
                a10 = __builtin_amdgcn_mfma_f32_16x16x32_bf16(afr[kb], b1f, a10, 0, 0, 0);
            }
        }
        f32x4 A0 = a00 + a01, A1 = a10 + a11;

        const unsigned short xs0[4] = {x0.x, x0.y, x0.z, x0.w};
        const unsigned short xs1[4] = {x1.x, x1.y, x1.z, x1.w};
        float hreg[4] = {0.f, 0.f, 0.f, 0.f};
#pragma unroll
        for (int r = 0; r < 4; ++r) {
            float v0 = A0[r] + b2f(xs0[r]);
            float v1 = A1[r] + b2f(xs1[r]);
            float p0 = __shfl_xor(v0, 8, 64);
            float p1 = __shfl_xor(v1, 8, 64);
            float ipre = halfsel ? p0 : v0;
            float fpre = halfsel ? v0 : p0;
            float gpre = halfsel ? p1 : v1;
            float opre = halfsel ? v1 : p1;
            if (!halfsel) {
                float ig = 1.0f / (1.0f + __expf(-ipre));
                float fg = 1.0f / (1.0f + __expf(-fpre));
                float gg = tanhf(gpre);
                float og = 1.0f / (1.0f + __expf(-opre));
                float cnew = fg * creg[r] + ig * gg;
                float hnew = og * tanhf(cnew);
                creg[r] = cnew;
                hreg[r] = hnew;
                sPack[(b0 + r) * 8 + u] = __float2bfloat16(hnew);
            }
        }

        __syncthreads();                         // sPack visible block-wide (only barrier/step)

        if (t == T_STEPS - 1) {
            if (!halfsel) {
#pragma unroll
                for (int r = 0; r < 4; ++r) {
                    int b = b0 + r;
                    out[(size_t)t * (BATCH * DH) + b * DH + jout] = hreg[r];
                    out[(size_t)T_STEPS * BATCH * DH + b * DH + jout] = hreg[r];
                    out[(size_t)T_STEPS * BATCH * DH + BATCH * DH + b * DH + jout] = creg[r];
                }
            }
        } else {
            // wave 0 alone stores the block's entire 1KB h slice (issued FIRST
            // so it is the oldest outstanding VMEM op of this wave); sc0 sc1 ->
            // lands at the LLC, no dirty L2 lines
            if (w == 0) {
                u32x4 hq = *(const u32x4*)&sPack[l * 8];   // 16B per lane
                asm volatile("global_store_dwordx4 %0, %1, %2 sc0 sc1"
                             :: "v"((unsigned)(l * 16)), "v"(hq), "s"(hob)
                             : "memory");
            }
            // out stores (all waves): issued after h-store, NOT waited on —
            // their HBM RMW acks retire in the background during the poll
            if (!halfsel) {
#pragma unroll
                for (int r = 0; r < 4; ++r)
                    out[(size_t)t * (BATCH * DH) + (b0 + r) * DH + jout] = hreg[r];
            }
            if (w == 0) {
                // vmcnt counts in issue order: wave0 has 1 h-store + 4 out
                // stores outstanding; vmcnt(4) waits exactly the h-store.
                asm volatile("s_waitcnt vmcnt(4)" ::: "memory");
                if (tid == 0) llc_store32(&flags[bk], (unsigned)(t + 2));
            }
            // all-wave busy poll: lane l checks flags[2l], flags[2l+1]
            const unsigned need = (unsigned)(t + 2);
            while (true) {
                u64 fv = llc_load64(f64 + l);
                if ((unsigned)fv >= need && (unsigned)(fv >> 32) >= need) break;
            }
            // acquire: stale L1/L2 lines (h buffer reused from 3 steps ago)
            // invalidated before the next step's plain h loads
            __builtin_amdgcn_fence(__ATOMIC_ACQUIRE, "agent");
            __builtin_amdgcn_sched_barrier(0);
        }
    }
}

extern "C" void kernel_launch(void* const* d_in, const int* in_sizes, int n_in,
                              void* d_out, int out_size, void* d_ws, size_t ws_size,
                              hipStream_t stream) {
    const int*   xs  = (const int*)d_in[0];
    const float* emb = (const float*)d_in[1];
    const float* Wih = (const float*)d_in[2];
    const float* Whh = (const float*)d_in[3];
    const float* bih = (const float*)d_in[4];
    const float* bhh = (const float*)d_in[5];
    float* out = (float*)d_out;
    char*  ws  = (char*)d_ws;

    __hip_bfloat16* Wih_bf = (__hip_bfloat16*)(ws);                  //  4 MB
    __hip_bfloat16* Whh_bf = (__hip_bfloat16*)(ws + 4194304);        //  8 MB
    __hip_bfloat16* e_bf   = (__hip_bfloat16*)(ws + 12582912);       // 16 MB
    __hip_bfloat16* xgp    = (__hip_bfloat16*)(ws + 29360128);       // 128 MB
    __hip_bfloat16* hbuf   = (__hip_bfloat16*)(ws + 163577856);      // 384 KB (3 bufs)
    unsigned*       flags  = (unsigned*)(ws + 163971072);            // 512 B

    hipMemsetAsync(flags, 0, 512, stream);
    k_f32_to_bf16<<<1024, 256, 0, stream>>>(Wih, Wih_bf, 2097152 / 8);
    k_f32_to_bf16<<<2048, 256, 0, stream>>>(Whh, Whh_bf, 4194304 / 8);
    k_gather<<<4096, 256, 0, stream>>>(xs, emb, e_bf);
    k_gemm_xg<<<4096, 256, 0, stream>>>(e_bf, Wih_bf, bih, bhh, xgp);
    k_lstm<<<NBLK, 256, 0, stream>>>(xgp, Whh_bf, hbuf, out, flags);
}